// Round 13
// baseline (224.367 us; speedup 1.0000x reference)
//
#include <hip/hip_runtime.h>
#include <hip/hip_bf16.h>
#include <math.h>

#define B 16
#define C 256
#define H 64
#define W 64
#define H2 32
#define W2 32
#define HW2 1024
#define HEADS 8
#define DH 32

typedef unsigned short ushort_t;
using short8 = __attribute__((ext_vector_type(8))) short;
using u16x8  = __attribute__((ext_vector_type(8))) unsigned short;
using f32x4  = __attribute__((ext_vector_type(4))) float;
using f32x16 = __attribute__((ext_vector_type(16))) float;

__device__ inline ushort_t f2bf(float f) {
    __hip_bfloat16 hb = __float2bfloat16(f);
    return *(ushort_t*)&hb;
}
__device__ inline float bf2f(ushort_t u) {
    return __uint_as_float(((unsigned)u) << 16);
}

// async global->LDS 16B DMA: LDS dest = wave-uniform base + lane*16 (linear),
// per-lane global source carries the swizzle (rule 21).
__device__ __forceinline__ void cp16(const ushort_t* g, ushort_t* l) {
    __builtin_amdgcn_global_load_lds(
        (const __attribute__((address_space(1))) void*)g,
        (__attribute__((address_space(3))) void*)l, 16, 0, 0);
}

#define RSCALE 0.17677669529663687f  // 1/sqrt(32)

// ---------- prep: all weights -> bf16, transposed/reordered (merged) ----------
// mat 0..2: wq/wk/wv -> wqkvT; mat 3: wo -> woT; mat 4: fr_w -> wfr;
// mat 5: conv_w [o][i][3][3] fp32 -> wbfT [kk][o][i] bf16.
__global__ __launch_bounds__(256) void k_prep_wx(
    const float* __restrict__ wq, const float* __restrict__ wk,
    const float* __restrict__ wv, const float* __restrict__ wo,
    const float* __restrict__ frw, const float* __restrict__ cw,
    ushort_t* __restrict__ wqkvT, ushort_t* __restrict__ woT,
    ushort_t* __restrict__ wfr, ushort_t* __restrict__ wbfT) {
    int op = blockIdx.x, mat = blockIdx.y, t = threadIdx.x;
    if (mat < 3) {
        const float* w = (mat == 0) ? wq : (mat == 1) ? wk : wv;
        int hh = op >> 5, d = op & 31, col = d * 8 + hh;
        wqkvT[(size_t)mat * 65536 + op * 256 + t] = f2bf(w[t * 256 + col]);
    } else if (mat == 3) {
        int hh = t >> 5, d = t & 31, ic = d * 8 + hh;
        woT[op * 256 + t] = f2bf(wo[ic * 256 + op]);
    } else if (mat == 4) {
        wfr[op * 256 + t] = f2bf(frw[op * 256 + t]);
    } else {
        const float* src = cw + ((size_t)op * C + t) * 9;
#pragma unroll
        for (int kk = 0; kk < 9; kk++)
            wbfT[((size_t)kk * C + op) * C + t] = f2bf(src[kk]);
    }
}

// ---------- prep: x NCHW fp32 -> xn [b][66][66][256] bf16 (LDS transpose) ----------
// Coalesced reads (256B/wave plane rows) -> ldsT[64][258] -> coalesced writes.
__global__ __launch_bounds__(256) void k_prep_xn(const float* __restrict__ x,
                                                 ushort_t* __restrict__ xn) {
    __shared__ ushort_t ldsT[64 * 258];  // pad 258: conflict-free both phases
    int t = threadIdx.x;
    int hp = blockIdx.x, b = blockIdx.y;
    ushort_t* dst = xn + ((size_t)(b * 66 + hp)) * 66 * 256;

    if (hp == 0 || hp == 65) {  // border h rows: all zeros (66*256 = 2112 x u16x8)
        u16x8 z = (u16x8){0, 0, 0, 0, 0, 0, 0, 0};
        for (int i = t; i < 2112; i += 256) *(u16x8*)(dst + i * 8) = z;
        return;
    }
    // phase 1: read 256 c-planes' row (hp-1), coalesced along w; transpose to LDS
    const float* xb = x + ((size_t)b * 256) * 4096 + (size_t)(hp - 1) * 64;
    {
        int cq = t >> 6, w = t & 63;
#pragma unroll 8
        for (int it = 0; it < 64; ++it) {
            int c = it * 4 + cq;
            float v = xb[(size_t)c * 4096 + w];
            ldsT[w * 258 + c] = f2bf(v);  // bank = (129*w + c/2)%32: 2-way max
        }
    }
    __syncthreads();
    // zero wp borders (wp=0 and wp=65)
    {
        u16x8 z = (u16x8){0, 0, 0, 0, 0, 0, 0, 0};
        if (t < 32) *(u16x8*)(dst + t * 8) = z;
        else if (t < 64) *(u16x8*)(dst + 65 * 256 + (t - 32) * 8) = z;
    }
    // phase 2: write interior wp=1..64, coalesced along c (b32 granule)
    {
        int half = t >> 7, cl = t & 127;
#pragma unroll 4
        for (int it = 0; it < 32; ++it) {
            int w = it * 2 + half;  // 0..63
            unsigned v = *(const unsigned*)&ldsT[w * 258 + cl * 2];
            *(unsigned*)(dst + (size_t)(w + 1) * 256 + cl * 2) = v;
        }
    }
}

// ---------- K1: 1x1 conv MFMA + bias + fused 2x2 maxpool/argmax ----------
__global__ __launch_bounds__(256) void k_conv1pool_mfma(
    const ushort_t* __restrict__ xn, const ushort_t* __restrict__ wfr,
    const float* __restrict__ frb, ushort_t* __restrict__ Pbf,
    unsigned char* __restrict__ idx) {
    __shared__ __align__(16) ushort_t sh[32768];  // 64KB: staging / T[128][256]
    ushort_t* Als = sh;           // [2][128][32]
    ushort_t* Bls = sh + 8192;    // [2][256][32]
    int t = threadIdx.x;
    int wg = blockIdx.x;
    int mt = (wg & 7) * 64 + (wg >> 3);  // 512 wgs, XCD swizzle
    int b = mt >> 5;
    int h0 = (mt * 2) & 63;

    int r = t >> 2, p = t & 3;
    int kswz = (p ^ ((r >> 1) & 3)) * 8;  // 2-way-max bank pattern
    const ushort_t* aB0 = xn + ((size_t)((b * 66 + h0 + 1) * 66 + (r + 1))) * 256 + kswz;
    const ushort_t* aB1 = xn + ((size_t)((b * 66 + h0 + 2) * 66 + (r + 1))) * 256 + kswz;
    const ushort_t* bB = wfr + (size_t)r * 256 + kswz;

    f32x4 acc[4][8];
#pragma unroll
    for (int mf = 0; mf < 4; mf++)
#pragma unroll
        for (int nf = 0; nf < 8; nf++) acc[mf][nf] = (f32x4){0.f, 0.f, 0.f, 0.f};

    cp16(aB0, &Als[t * 8]);
    cp16(aB1, &Als[2048 + t * 8]);
    cp16(bB, &Bls[t * 8]);
    cp16(bB + 64 * 256, &Bls[2048 + t * 8]);
    cp16(bB + 128 * 256, &Bls[4096 + t * 8]);
    cp16(bB + 192 * 256, &Bls[6144 + t * 8]);
    __syncthreads();

    int l = t & 63, wid = t >> 6, wm = wid >> 1, wn = wid & 1;
    int arow = wm * 64 + (l & 15);
    int brow = wn * 128 + (l & 15);
    int pslot = ((l >> 4) ^ ((l >> 1) & 3)) * 8;

    for (int s = 0; s < 8; s++) {
        int cur = s & 1;
        if (s < 7) {
            int off = (s + 1) * 32;
            int nb = cur ^ 1;
            cp16(aB0 + off, &Als[nb * 4096 + t * 8]);
            cp16(aB1 + off, &Als[nb * 4096 + 2048 + t * 8]);
            cp16(bB + off, &Bls[nb * 8192 + t * 8]);
            cp16(bB + 64 * 256 + off, &Bls[nb * 8192 + 2048 + t * 8]);
            cp16(bB + 128 * 256 + off, &Bls[nb * 8192 + 4096 + t * 8]);
            cp16(bB + 192 * 256 + off, &Bls[nb * 8192 + 6144 + t * 8]);
        }
        short8 af[4], bf[8];
#pragma unroll
        for (int mf = 0; mf < 4; mf++)
            af[mf] = *(const short8*)&Als[cur * 4096 + (arow + mf * 16) * 32 + pslot];
#pragma unroll
        for (int nf = 0; nf < 8; nf++)
            bf[nf] = *(const short8*)&Bls[cur * 8192 + (brow + nf * 16) * 32 + pslot];
#pragma unroll
        for (int mf = 0; mf < 4; mf++)
#pragma unroll
            for (int nf = 0; nf < 8; nf++)
                acc[mf][nf] = __builtin_amdgcn_mfma_f32_16x16x32_bf16(
                    af[mf], bf[nf], acc[mf][nf], 0, 0, 0);
        __syncthreads();
    }

    // ---- write conv result (+bias) to LDS tile T[128][256] bf16 ----
#pragma unroll
    for (int nf = 0; nf < 8; nf++) {
        int o = wn * 128 + nf * 16 + (l & 15);
        float bias = frb[o];
#pragma unroll
        for (int mf = 0; mf < 4; mf++) {
            int rbase = wm * 64 + mf * 16 + ((l >> 4) << 2);
            f32x4 a = acc[mf][nf];
#pragma unroll
            for (int jj = 0; jj < 4; jj++)
                sh[(rbase + jj) * 256 + o] = f2bf(a[jj] + bias);
        }
    }
    __syncthreads();

    // ---- pool (vectorized): thread = (w2, 8-o group); b128 row reads ----
    {
        int h2 = mt & 31;
        size_t rowb = (size_t)(b << 10) + h2 * 32;
        int o0 = (t & 31) * 8;
#pragma unroll
        for (int pp = 0; pp < 4; pp++) {
            int w2 = pp * 8 + (t >> 5);
            u16x8 r0 = *(const u16x8*)&sh[(2 * w2) * 256 + o0];
            u16x8 r1 = *(const u16x8*)&sh[(2 * w2 + 1) * 256 + o0];
            u16x8 r2 = *(const u16x8*)&sh[(64 + 2 * w2) * 256 + o0];
            u16x8 r3 = *(const u16x8*)&sh[(64 + 2 * w2 + 1) * 256 + o0];
            u16x8 pv;
            unsigned amlo = 0, amhi = 0;
#pragma unroll
            for (int e = 0; e < 8; e++) {
                float v0 = bf2f(r0[e]), v1 = bf2f(r1[e]);
                float v2 = bf2f(r2[e]), v3 = bf2f(r3[e]);
                float m = v0;
                ushort_t raw = r0[e];
                unsigned am = 0;
                if (v1 > m) { m = v1; raw = r1[e]; am = 1; }
                if (v2 > m) { m = v2; raw = r2[e]; am = 2; }
                if (v3 > m) { m = v3; raw = r3[e]; am = 3; }
                pv[e] = raw;
                if (e < 4) amlo |= am << (8 * e);
                else       amhi |= am << (8 * (e - 4));
            }
            size_t po = (rowb + w2) * 256 + o0;
            *(u16x8*)(Pbf + po) = pv;
            *(uint2*)(idx + po) = make_uint2(amlo, amhi);
        }
    }
}

// ---------- K2a: QKV MFMA GEMM. q prescaled by RSCALE; v stored transposed ----------
__global__ __launch_bounds__(256) void k_qkv_mfma(
    const ushort_t* __restrict__ A, const ushort_t* __restrict__ Bw,
    ushort_t* __restrict__ qb, ushort_t* __restrict__ kb,
    ushort_t* __restrict__ vtb) {
    __shared__ __align__(16) ushort_t Als[2][4096];
    __shared__ __align__(16) ushort_t Bls[2][4096];
    int t = threadIdx.x;
    int wg = blockIdx.x;
    int linear = (wg & 7) * 96 + (wg >> 3);  // 768 wgs; nt inner for A reuse
    int mt = linear / 6, nt = linear % 6;

    int r = t >> 2, p = t & 3;
    int kswz = (p ^ ((r >> 1) & 3)) * 8;
    const ushort_t* aB0 = A + ((size_t)(mt * 128 + r)) * 256 + kswz;
    const ushort_t* aB1 = aB0 + (size_t)64 * 256;
    const ushort_t* bB0 = Bw + ((size_t)(nt * 128 + r)) * 256 + kswz;
    const ushort_t* bB1 = bB0 + (size_t)64 * 256;

    f32x4 acc[4][4];
#pragma unroll
    for (int mf = 0; mf < 4; mf++)
#pragma unroll
        for (int nf = 0; nf < 4; nf++) acc[mf][nf] = (f32x4){0.f, 0.f, 0.f, 0.f};

    cp16(aB0, &Als[0][t * 8]);
    cp16(aB1, &Als[0][2048 + t * 8]);
    cp16(bB0, &Bls[0][t * 8]);
    cp16(bB1, &Bls[0][2048 + t * 8]);
    __syncthreads();

    int l = t & 63, wid = t >> 6, wm = wid >> 1, wn = wid & 1;
    int arow = wm * 64 + (l & 15);
    int brow = wn * 64 + (l & 15);
    int pslot = ((l >> 4) ^ ((l >> 1) & 3)) * 8;

    for (int s = 0; s < 8; s++) {
        int cur = s & 1;
        if (s < 7) {
            int off = (s + 1) * 32;
            int nb = cur ^ 1;
            cp16(aB0 + off, &Als[nb][t * 8]);
            cp16(aB1 + off, &Als[nb][2048 + t * 8]);
            cp16(bB0 + off, &Bls[nb][t * 8]);
            cp16(bB1 + off, &Bls[nb][2048 + t * 8]);
        }
        short8 af[4], bf[4];
#pragma unroll
        for (int mf = 0; mf < 4; mf++)
            af[mf] = *(const short8*)&Als[cur][(arow + mf * 16) * 32 + pslot];
#pragma unroll
        for (int nf = 0; nf < 4; nf++)
            bf[nf] = *(const short8*)&Bls[cur][(brow + nf * 16) * 32 + pslot];
#pragma unroll
        for (int mf = 0; mf < 4; mf++)
#pragma unroll
            for (int nf = 0; nf < 4; nf++)
                acc[mf][nf] = __builtin_amdgcn_mfma_f32_16x16x32_bf16(
                    af[mf], bf[nf], acc[mf][nf], 0, 0, 0);
        __syncthreads();
    }

    if (nt < 4) {
        // q (scaled) / k: [m][256] bf16 scatter
        ushort_t* dst = (nt < 2) ? qb : kb;
        float sc = (nt < 2) ? RSCALE : 1.0f;
        int ccb = (nt & 1) * 128 + wn * 64;
#pragma unroll
        for (int nf = 0; nf < 4; nf++) {
            int cc = ccb + nf * 16 + (l & 15);
#pragma unroll
            for (int mf = 0; mf < 4; mf++) {
                int m = mt * 128 + wm * 64 + mf * 16 + ((l >> 4) << 2);
                f32x4 a = acc[mf][nf];
#pragma unroll
                for (int jj = 0; jj < 4; jj++)
                    dst[(size_t)(m + jj) * 256 + cc] = f2bf(a[jj] * sc);
            }
        }
    } else {
        // v transposed: vtb[(b*256 + cc)][n], 4 consecutive n per lane -> uint2
#pragma unroll
        for (int nf = 0; nf < 4; nf++) {
            int cc = (nt & 1) * 128 + wn * 64 + nf * 16 + (l & 15);
#pragma unroll
            for (int mf = 0; mf < 4; mf++) {
                int m = mt * 128 + wm * 64 + mf * 16 + ((l >> 4) << 2);
                int b = m >> 10, n0 = m & 1023;
                f32x4 a = acc[mf][nf];
                unsigned u0 = ((unsigned)f2bf(a[1]) << 16) | f2bf(a[0]);
                unsigned u1 = ((unsigned)f2bf(a[3]) << 16) | f2bf(a[2]);
                *(uint2*)&vtb[((size_t)(b * 256 + cc)) * 1024 + n0] =
                    make_uint2(u0, u1);
            }
        }
    }
}

// ---------- K2b: MFMA flash attention (swapped QK^T, wave-private P_lds) ----------
__global__ __launch_bounds__(256) void k_attn_mfma(
    const ushort_t* __restrict__ qb, const ushort_t* __restrict__ kb,
    const ushort_t* __restrict__ vtb, ushort_t* __restrict__ aoT) {
    __shared__ __align__(16) ushort_t Klds[2][2048];   // [64 k][32 d] swizzled
    __shared__ __align__(16) ushort_t Vlds[2][2048];   // [32 d][64 n] swizzled
    __shared__ __align__(16) ushort_t Plds[4][2304];   // per-wave [32 q][72]
    __shared__ float rs_lds[128];

    int t = threadIdx.x;
    int bid = blockIdx.x;
    int swz = (bid & 7) * 128 + (bid >> 3);
    int bh = swz >> 3, qt = swz & 7;
    int b = bh >> 3, h = bh & 7;
    int w = t >> 6, l = t & 63, g = l >> 4, li = l & 15;

    // Q B-frags
    size_t qrow = (size_t)(b * 1024 + qt * 128 + w * 32 + li);
    short8 qv0 = *(const short8*)(qb + qrow * 256 + h * 32 + g * 8);
    short8 qv1 = *(const short8*)(qb + (qrow + 16) * 256 + h * 32 + g * 8);

    // staging addresses (XOR-preswizzled global source, linear LDS dest)
    int sr = t >> 2, sp = t & 3;
    const ushort_t* kg =
        kb + ((size_t)(b * 1024 + sr)) * 256 + h * 32 + ((sp ^ ((sr >> 1) & 3)) * 8);
    int vd = t >> 3, vs = t & 7;
    const ushort_t* vg =
        vtb + ((size_t)(b * 256 + h * 32 + vd)) * 1024 + ((vs ^ (vd & 7)) * 8);

    f32x4 oacc[2][2];
    f32x4 rsv[2];
#pragma unroll
    for (int qf = 0; qf < 2; qf++) {
        rsv[qf] = (f32x4){0.f, 0.f, 0.f, 0.f};
#pragma unroll
        for (int df = 0; df < 2; df++) oacc[qf][df] = (f32x4){0.f, 0.f, 0.f, 0.f};
    }

    cp16(kg, &Klds[0][t * 8]);
    cp16(vg, &Vlds[0][t * 8]);
    __syncthreads();

    ushort_t* Pw = &Plds[w][0];

    for (int c = 0; c < 16; c++) {
        int cur = c & 1;
        if (c < 15) {  // async prefetch next chunk; drains at this step's barrier
            cp16(kg + (size_t)(c + 1) * 64 * 256, &Klds[cur ^ 1][t * 8]);
            cp16(vg + (c + 1) * 64, &Vlds[cur ^ 1][t * 8]);
        }
        // S^T frags: A = K rows, B = Q rows. D: col=q(li), row=k(4g+reg)
        short8 ak[4];
#pragma unroll
        for (int kf = 0; kf < 4; kf++)
            ak[kf] = *(const short8*)&Klds[cur][(16 * kf + li) * 32 +
                                               ((g ^ ((l >> 1) & 3)) * 8)];
#pragma unroll
        for (int qf = 0; qf < 2; qf++) {
            short8 qv = qf ? qv1 : qv0;
#pragma unroll
            for (int kf = 0; kf < 4; kf++) {
                f32x4 st = __builtin_amdgcn_mfma_f32_16x16x32_bf16(
                    ak[kf], qv, (f32x4){0.f, 0.f, 0.f, 0.f}, 0, 0, 0);
                float p0 = __expf(st[0]), p1 = __expf(st[1]);
                float p2 = __expf(st[2]), p3 = __expf(st[3]);
                rsv[qf][0] += p0; rsv[qf][1] += p1;
                rsv[qf][2] += p2; rsv[qf][3] += p3;
                unsigned u0, u1;
                asm("v_cvt_pk_bf16_f32 %0, %1, %2" : "=v"(u0) : "v"(p0), "v"(p1));
                asm("v_cvt_pk_bf16_f32 %0, %1, %2" : "=v"(u1) : "v"(p2), "v"(p3));
                *(uint2*)&Pw[(16 * qf + li) * 72 + 16 * kf + 4 * g] =
                    make_uint2(u0, u1);
            }
        }
        // PV: A = P rows (q), B = vT rows (d). D: col=d(li), row=q(4g+reg)
#pragma unroll
        for (int win = 0; win < 2; win++) {
            short8 pa[2], bv[2];
#pragma unroll
            for (int qf = 0; qf < 2; qf++)
                pa[qf] = *(const short8*)&Pw[(16 * qf + li) * 72 + win * 32 + 8 * g];
#pragma unroll
            for (int df = 0; df < 2; df++)
                bv[df] = *(const short8*)&Vlds[cur][(16 * df + li) * 64 +
                                                    (((win * 4 + g) ^ (l & 7)) * 8)];
#pragma unroll
            for (int qf = 0; qf < 2; qf++)
#pragma unroll
                for (int df = 0; df < 2; df++)
                    oacc[qf][df] = __builtin_amdgcn_mfma_f32_16x16x32_bf16(
                        pa[qf], bv[df], oacc[qf][df], 0, 0, 0);
        }
        __syncthreads();
    }

    // row-sum: reduce partials over the 4 g-groups
#pragma unroll
    for (int qf = 0; qf < 2; qf++) {
        float rs = (rsv[qf][0] + rsv[qf][1]) + (rsv[qf][2] + rsv[qf][3]);
        rs += __shfl_xor(rs, 16);
        rs += __shfl_xor(rs, 32);
        if (l < 16) rs_lds[w * 32 + 16 * qf + li] = rs;
    }
    __syncthreads();

    // epilogue: O lane holds q = 16qf + 4g + reg, d = 16df + li
#pragma unroll
    for (int qf = 0; qf < 2; qf++) {
        float4 rs4 = *(const float4*)&rs_lds[w * 32 + 16 * qf + 4 * g];
        float inv[4] = {1.f / rs4.x, 1.f / rs4.y, 1.f / rs4.z, 1.f / rs4.w};
#pragma unroll
        for (int df = 0; df < 2; df++) {
            f32x4 a = oacc[qf][df];
#pragma unroll
            for (int r2 = 0; r2 < 4; r2++) {
                size_t row = (size_t)(b * 1024 + qt * 128 + w * 32 + 16 * qf +
                                      4 * g + r2);
                aoT[row * 256 + h * 32 + 16 * df + li] = f2bf(a[r2] * inv[r2]);
            }
        }
    }
}

// ---------- K2c: output projection MFMA -> y2 [b][n][o] fp32 ----------
__global__ __launch_bounds__(256) void k_oproj_mfma(
    const ushort_t* __restrict__ A, const ushort_t* __restrict__ Bw,
    float* __restrict__ y2) {
    __shared__ __align__(16) ushort_t Als[2][4096];
    __shared__ __align__(16) ushort_t Bls[2][4096];
    int t = threadIdx.x;
    int wg = blockIdx.x;
    int linear = (wg & 7) * 32 + (wg >> 3);  // 256 wgs; nt inner
    int nt = linear & 1, mt = linear >> 1;

    int r = t >> 2, p = t & 3;
    int kswz = (p ^ ((r >> 1) & 3)) * 8;
    const ushort_t* aB0 = A + ((size_t)(mt * 128 + r)) * 256 + kswz;
    const ushort_t* aB1 = aB0 + (size_t)64 * 256;
    const ushort_t* bB0 = Bw + ((size_t)(nt * 128 + r)) * 256 + kswz;
    const ushort_t* bB1 = bB0 + (size_t)64 * 256;

    f32x4 acc[4][4];
#pragma unroll
    for (int mf = 0; mf < 4; mf++)
#pragma unroll
        for (int nf = 0; nf < 4; nf++) acc[mf][nf] = (f32x4){0.f, 0.f, 0.f, 0.f};

    cp16(aB0, &Als[0][t * 8]);
    cp16(aB1, &Als[0][2048 + t * 8]);
    cp16(bB0, &Bls[0][t * 8]);
    cp16(bB1, &Bls[0][2048 + t * 8]);
    __syncthreads();

    int l = t & 63, wid = t >> 6, wm = wid >> 1, wn = wid & 1;
    int arow = wm * 64 + (l & 15);
    int brow = wn * 64 + (l & 15);
    int pslot = ((l >> 4) ^ ((l >> 1) & 3)) * 8;

    for (int s = 0; s < 8; s++) {
        int cur = s & 1;
        if (s < 7) {
            int off = (s + 1) * 32;
            int nb = cur ^ 1;
            cp16(aB0 + off, &Als[nb][t * 8]);
            cp16(aB1 + off, &Als[nb][2048 + t * 8]);
            cp16(bB0 + off, &Bls[nb][t * 8]);
            cp16(bB1 + off, &Bls[nb][2048 + t * 8]);
        }
        short8 af[4], bf[4];
#pragma unroll
        for (int mf = 0; mf < 4; mf++)
            af[mf] = *(const short8*)&Als[cur][(arow + mf * 16) * 32 + pslot];
#pragma unroll
        for (int nf = 0; nf < 4; nf++)
            bf[nf] = *(const short8*)&Bls[cur][(brow + nf * 16) * 32 + pslot];
#pragma unroll
        for (int mf = 0; mf < 4; mf++)
#pragma unroll
            for (int nf = 0; nf < 4; nf++)
                acc[mf][nf] = __builtin_amdgcn_mfma_f32_16x16x32_bf16(
                    af[mf], bf[nf], acc[mf][nf], 0, 0, 0);
        __syncthreads();
    }

#pragma unroll
    for (int nf = 0; nf < 4; nf++) {
        int cc = nt * 128 + wn * 64 + nf * 16 + (l & 15);
#pragma unroll
        for (int mf = 0; mf < 4; mf++) {
            int m = mt * 128 + wm * 64 + mf * 16 + ((l >> 4) << 2);
            f32x4 a = acc[mf][nf];
#pragma unroll
            for (int jj = 0; jj < 4; jj++)
                y2[(size_t)(m + jj) * 256 + cc] = a[jj];
        }
    }
}

// ---------- K3: implicit-GEMM bf16 MFMA 3x3 conv ----------
// Round-13: round-9 structure (BM=128 BN=256 BK=32, 8 waves, 2 blocks/CU,
// 3 LDS buffers, counted vmcnt(3) + raw s_barrier) with the MFMA swapped to
// v_mfma_f32_32x32x16_bf16: 8 MFMA/wave/kt instead of 16 (same FLOPs) at the
// higher 32x32 ceiling (2382 vs 2075 TF) and half the issue slots. LDS reads
// unchanged: 8 b128/wave/kt (A: 2 am x 2 kk, B: 2 bn x 2 kk; lane supplies
// row/col = l&31, k-chunk = kk*2 + (l>>5)). Bank audit: every consecutive
// 8-lane batch hits all 8 distinct 16B groups -> conflict-free like before.
// C/D layout (m74/m101): col = lane&31, row = (reg&3) + 8*(reg>>2) +
// 4*(lane>>5); reg-quads give 4 consecutive m -> float4 stores kept.
// K=32 now accumulates via 2 instructions (kk asc) - order change only.
__global__ __launch_bounds__(512, 4) void k_conv3_mfma(
    const ushort_t* __restrict__ xn, const ushort_t* __restrict__ wbfT,
    const float* __restrict__ cb, const float* __restrict__ y2,
    const unsigned char* __restrict__ idx, const float* __restrict__ gamma,
    float* __restrict__ out) {
    extern __shared__ __align__(16) ushort_t lds[];  // 3 bufs x 12288 ushorts
    int t = threadIdx.x;
    int wg = blockIdx.x;
    int mt = (wg & 7) * 64 + (wg >> 3);  // 512 wgs; XCD swizzle

    // staging: thread t covers (row t>>2, 16B slot t&3); swz f(row)=(row>>1)&3
    int srow = t >> 2, sslot = t & 3;
    int kel = (sslot ^ ((srow >> 1) & 3)) * 8;  // elements
    int m0 = mt * 128 + srow;
    int ab0 = m0 >> 12, ah0 = (m0 >> 6) & 63, aw0 = m0 & 63;
    const ushort_t* aP = xn + ((size_t)((ab0 * 66 + ah0) * 66 + aw0)) * 256 + kel;
    const ushort_t* bP0 = wbfT + (size_t)srow * 256 + kel;          // rows 0..127
    const ushort_t* bP1 = wbfT + (size_t)(srow + 128) * 256 + kel;  // rows 128..255

    // kt = it*9 + khkw; it in 0..7 (32-ch slice), khkw in 0..8 (spatial tap)
    auto offA = [](int kt) -> int {
        int it = kt / 9, khkw = kt - it * 9;
        int kh = khkw / 3, kw = khkw - kh * 3;
        return (kh * 66 + kw) * 256 + it * 32;
    };
    auto offB = [](int kt) -> int {
        int it = kt / 9, khkw = kt - it * 9;
        return khkw * 65536 + it * 32;
    };
    auto STAGE = [&](int bufi, int kt) {  // 3 cp16/thread: A 8KB + B 16KB
        ushort_t* base = lds + bufi * 12288;
        cp16(aP + offA(kt), base + t * 8);
        int ob = offB(kt);
        cp16(bP0 + ob, base + 4096 + t * 8);
        cp16(bP1 + ob, base + 8192 + t * 8);
    };

    f32x16 acc[2][2];
#pragma unroll
    for (int am = 0; am < 2; am++)
#pragma unroll
        for (int bn = 0; bn < 2; bn++)
#pragma unroll
            for (int e = 0; e < 16; e++) acc[am][bn][e] = 0.f;

    int l = t & 63, wid = t >> 6, wm = wid >> 2, wn = wid & 3;
    int r31 = l & 31, hh = l >> 5;
    int sw3 = (r31 >> 1) & 3;  // read-side XOR (cancels staging swizzle)

    // prologue: tiles 0,1 in flight; drain tile 0; barrier
    STAGE(0, 0);
    STAGE(1, 1);
    __builtin_amdgcn_sched_barrier(0);
    asm volatile("s_waitcnt vmcnt(3)" ::: "memory");
    __builtin_amdgcn_sched_barrier(0);
    __builtin_amdgcn_s_barrier();
    __builtin_amdgcn_sched_barrier(0);

    for (int kt = 0; kt < 72; kt++) {
        int cur = kt % 3;
        const ushort_t* base = lds + cur * 12288;
        if (kt < 70) STAGE((kt + 2) % 3, kt + 2);
        short8 af[2][2], bf[2][2];  // [am|bn][kk]
#pragma unroll
        for (int am = 0; am < 2; am++)
#pragma unroll
            for (int kk = 0; kk < 2; kk++)
                af[am][kk] = *(const short8*)
                    &base[(wm * 64 + am * 32 + r31) * 32 +
                          (((kk * 2 + hh) ^ sw3) * 8)];
#pragma unroll
        for (int bn = 0; bn < 2; bn++)
#pragma unroll
            for (int kk = 0; kk < 2; kk++)
                bf[bn][kk] = *(const short8*)
                    &base[4096 + (wn * 64 + bn * 32 + r31) * 32 +
                          (((kk * 2 + hh) ^ sw3) * 8)];
        __builtin_amdgcn_s_setprio(1);
#pragma unroll
        for (int kk = 0; kk < 2; kk++)
#pragma unroll
            for (int am = 0; am < 2; am++)
#pragma unroll
                for (int bn = 0; bn < 2; bn++)
                    acc[am][bn] = __builtin_amdgcn_mfma_f32_32x32x16_bf16(
                        af[am][kk], bf[bn][kk], acc[am][bn], 0, 0, 0);
        __builtin_amdgcn_s_setprio(0);
        __builtin_amdgcn_sched_barrier(0);
        if (kt < 70) {
            asm volatile("s_waitcnt vmcnt(3)" ::: "memory");  // drains kt+1's 3
        } else {
            asm volatile("s_waitcnt vmcnt(0)" ::: "memory");
        }
        __builtin_amdgcn_sched_barrier(0);
        __builtin_amdgcn_s_barrier();
        __builtin_amdgcn_sched_barrier(0);
    }

    // epilogue: D col = lane&31, row = (reg&3) + 8*(reg>>2) + 4*(lane>>5)
    float tg = tanhf(gamma[0]);
#pragma unroll
    for (int bn = 0; bn < 2; bn++) {
        int o = wn * 64 + bn * 32 + r31;
        float bias = cb[o];
#pragma unroll
        for (int am = 0; am < 2; am++) {
#pragma unroll
            for (int q = 0; q < 4; q++) {
                int m = mt * 128 + wm * 64 + am * 32 + q * 8 + 4 * hh;
                int b = m >> 12, h = (m >> 6) & 63, w0 = m & 63;
                const unsigned char* idr = idx + ((size_t)(b << 10)) * 256;
                const float* y2r = y2 + ((size_t)(b << 10)) * 256;
                float v4[4];
#pragma unroll
                for (int jj = 0; jj < 4; jj++) {
                    int wj = w0 + jj;
                    int n2 = ((h >> 1) << 5) + (wj >> 1);
                    int j2 = ((h & 1) << 1) + (wj & 1);
                    float val = acc[am][bn][q * 4 + jj] + bias;
                    if (idr[(size_t)n2 * 256 + o] == (unsigned char)j2)
                        val += tg * y2r[(size_t)n2 * 256 + o];
                    v4[jj] = val;
                }
                *(float4*)(out + (((size_t)(b * C + o) * H + h) << 6) + w0) =
                    make_float4(v4[0], v4[1], v4[2], v4[3]);
            }
        }
    }
}

extern "C" void kernel_launch(void* const* d_in, const int* in_sizes, int n_in,
                              void* d_out, int out_size, void* d_ws, size_t ws_size,
                              hipStream_t stream) {
    const float* x      = (const float*)d_in[0];
    const float* conv_w = (const float*)d_in[1];
    const float* conv_b = (const float*)d_in[2];
    const float* fr_w   = (const float*)d_in[3];
    const float* fr_b   = (const float*)d_in[4];
    const float* wq     = (const float*)d_in[5];
    const float* wk     = (const float*)d_in[6];
    const float* wv     = (const float*)d_in[7];
    const float* wo     = (const float*)d_in[8];
    const float* gamma  = (const float*)d_in[9];
    float* out = (float*)d_out;
    char* ws = (char*)d_ws;

    // ws layout (bytes), total 83.9 MB
    ushort_t* wbfT  = (ushort_t*)(ws + 0);           // 1,179,648
    ushort_t* wfrbf = (ushort_t*)(ws + 1179648);     // 131,072
    ushort_t* wqkvT = (ushort_t*)(ws + 1310720);     // 393,216
    ushort_t* woT   = (ushort_t*)(ws + 1703936);     // 131,072
    ushort_t* xn    = (ushort_t*)(ws + 2097152);     // 35,684,352
    ushort_t* Pbf   = (ushort_t*)(ws + 37781504);    // 8,388,608
    unsigned char* idx = (unsigned char*)(ws + 46170112);  // 4,194,304
    ushort_t* qb    = (ushort_t*)(ws + 50364416);    // 8,388,608
    ushort_t* kb    = (ushort_t*)(ws + 58753024);    // 8,388,608
    ushort_t* vtb   = (ushort_t*)(ws + 67141632);    // 8,388,608 (transposed V)
    ushort_t* aoT   = (ushort_t*)(ws + 75530240);    // 8,388,608 -> end 83,918,848
    float* y2       = (float*)(ws + 50364416);       // aliases qb+kb (dead after attn)

    k_prep_wx<<<dim3(256, 6), dim3(256), 0, stream>>>(wq, wk, wv, wo, fr_w, conv_w,
                                                      wqkvT, woT, wfrbf, wbfT);
    k_prep_xn<<<dim3(66, B), dim3(256), 0, stream>>>(x, xn);
    k_conv1pool_mfma<<<dim3(512), dim3(256), 0, stream>>>(xn, wfrbf, fr_b, Pbf, idx);
    k_qkv_mfma<<<dim3(768), dim3(256), 0, stream>>>(Pbf, wqkvT, qb, kb, vtb);
    k_attn_mfma<<<dim3(1024), dim3(256), 0, stream>>>(qb, kb, vtb, aoT);
    k_oproj_mfma<<<dim3(256), dim3(256), 0, stream>>>(aoT, woT, y2);
    (void)hipFuncSetAttribute(reinterpret_cast<const void*>(k_conv3_mfma),
                              hipFuncAttributeMaxDynamicSharedMemorySize, 73728);
    k_conv3_mfma<<<dim3(512), dim3(512), 73728, stream>>>(xn, wbfT, conv_b, y2, idx,
                                                          gamma, out);
    (void)in_sizes; (void)n_in; (void)out_size; (void)ws_size;
}

// Round 14
// 203.675 us; speedup vs baseline: 1.1016x; 1.1016x over previous
//
#include <hip/hip_runtime.h>
#include <hip/hip_bf16.h>
#include <math.h>

#define B 16
#define C 256
#define H 64
#define W 64
#define H2 32
#define W2 32
#define HW2 1024
#define HEADS 8
#define DH 32

typedef unsigned short ushort_t;
using short8 = __attribute__((ext_vector_type(8))) short;
using u16x8  = __attribute__((ext_vector_type(8))) unsigned short;
using f32x4  = __attribute__((ext_vector_type(4))) float;

__device__ inline ushort_t f2bf(float f) {
    __hip_bfloat16 hb = __float2bfloat16(f);
    return *(ushort_t*)&hb;
}
__device__ inline float bf2f(ushort_t u) {
    return __uint_as_float(((unsigned)u) << 16);
}

// async global->LDS 16B DMA: LDS dest = wave-uniform base + lane*16 (linear),
// per-lane global source carries the swizzle (rule 21).
__device__ __forceinline__ void cp16(const ushort_t* g, ushort_t* l) {
    __builtin_amdgcn_global_load_lds(
        (const __attribute__((address_space(1))) void*)g,
        (__attribute__((address_space(3))) void*)l, 16, 0, 0);
}

#define RSCALE 0.17677669529663687f  // 1/sqrt(32)

// ---------- prep: all weights -> bf16, transposed/reordered (merged) ----------
// mat 0..2: wq/wk/wv -> wqkvT; mat 3: wo -> woT; mat 4: fr_w -> wfr;
// mat 5: conv_w [o][i][3][3] fp32 -> wbfT [kk][o][i] bf16.
__global__ __launch_bounds__(256) void k_prep_wx(
    const float* __restrict__ wq, const float* __restrict__ wk,
    const float* __restrict__ wv, const float* __restrict__ wo,
    const float* __restrict__ frw, const float* __restrict__ cw,
    ushort_t* __restrict__ wqkvT, ushort_t* __restrict__ woT,
    ushort_t* __restrict__ wfr, ushort_t* __restrict__ wbfT) {
    int op = blockIdx.x, mat = blockIdx.y, t = threadIdx.x;
    if (mat < 3) {
        const float* w = (mat == 0) ? wq : (mat == 1) ? wk : wv;
        int hh = op >> 5, d = op & 31, col = d * 8 + hh;
        wqkvT[(size_t)mat * 65536 + op * 256 + t] = f2bf(w[t * 256 + col]);
    } else if (mat == 3) {
        int hh = t >> 5, d = t & 31, ic = d * 8 + hh;
        woT[op * 256 + t] = f2bf(wo[ic * 256 + op]);
    } else if (mat == 4) {
        wfr[op * 256 + t] = f2bf(frw[op * 256 + t]);
    } else {
        const float* src = cw + ((size_t)op * C + t) * 9;
#pragma unroll
        for (int kk = 0; kk < 9; kk++)
            wbfT[((size_t)kk * C + op) * C + t] = f2bf(src[kk]);
    }
}

// ---------- prep: x NCHW fp32 -> xn [b][66][66][256] bf16 (LDS transpose) ----------
// Coalesced reads (256B/wave plane rows) -> ldsT[64][258] -> coalesced writes.
__global__ __launch_bounds__(256) void k_prep_xn(const float* __restrict__ x,
                                                 ushort_t* __restrict__ xn) {
    __shared__ ushort_t ldsT[64 * 258];  // pad 258: conflict-free both phases
    int t = threadIdx.x;
    int hp = blockIdx.x, b = blockIdx.y;
    ushort_t* dst = xn + ((size_t)(b * 66 + hp)) * 66 * 256;

    if (hp == 0 || hp == 65) {  // border h rows: all zeros (66*256 = 2112 x u16x8)
        u16x8 z = (u16x8){0, 0, 0, 0, 0, 0, 0, 0};
        for (int i = t; i < 2112; i += 256) *(u16x8*)(dst + i * 8) = z;
        return;
    }
    // phase 1: read 256 c-planes' row (hp-1), coalesced along w; transpose to LDS
    const float* xb = x + ((size_t)b * 256) * 4096 + (size_t)(hp - 1) * 64;
    {
        int cq = t >> 6, w = t & 63;
#pragma unroll 8
        for (int it = 0; it < 64; ++it) {
            int c = it * 4 + cq;
            float v = xb[(size_t)c * 4096 + w];
            ldsT[w * 258 + c] = f2bf(v);  // bank = (129*w + c/2)%32: 2-way max
        }
    }
    __syncthreads();
    // zero wp borders (wp=0 and wp=65)
    {
        u16x8 z = (u16x8){0, 0, 0, 0, 0, 0, 0, 0};
        if (t < 32) *(u16x8*)(dst + t * 8) = z;
        else if (t < 64) *(u16x8*)(dst + 65 * 256 + (t - 32) * 8) = z;
    }
    // phase 2: write interior wp=1..64, coalesced along c (b32 granule)
    {
        int half = t >> 7, cl = t & 127;
#pragma unroll 4
        for (int it = 0; it < 32; ++it) {
            int w = it * 2 + half;  // 0..63
            unsigned v = *(const unsigned*)&ldsT[w * 258 + cl * 2];
            *(unsigned*)(dst + (size_t)(w + 1) * 256 + cl * 2) = v;
        }
    }
}

// ---------- K1: 1x1 conv MFMA + bias + fused 2x2 maxpool/argmax ----------
__global__ __launch_bounds__(256) void k_conv1pool_mfma(
    const ushort_t* __restrict__ xn, const ushort_t* __restrict__ wfr,
    const float* __restrict__ frb, ushort_t* __restrict__ Pbf,
    unsigned char* __restrict__ idx) {
    __shared__ __align__(16) ushort_t sh[32768];  // 64KB: staging / T[128][256]
    ushort_t* Als = sh;           // [2][128][32]
    ushort_t* Bls = sh + 8192;    // [2][256][32]
    int t = threadIdx.x;
    int wg = blockIdx.x;
    int mt = (wg & 7) * 64 + (wg >> 3);  // 512 wgs, XCD swizzle
    int b = mt >> 5;
    int h0 = (mt * 2) & 63;

    int r = t >> 2, p = t & 3;
    int kswz = (p ^ ((r >> 1) & 3)) * 8;  // 2-way-max bank pattern
    const ushort_t* aB0 = xn + ((size_t)((b * 66 + h0 + 1) * 66 + (r + 1))) * 256 + kswz;
    const ushort_t* aB1 = xn + ((size_t)((b * 66 + h0 + 2) * 66 + (r + 1))) * 256 + kswz;
    const ushort_t* bB = wfr + (size_t)r * 256 + kswz;

    f32x4 acc[4][8];
#pragma unroll
    for (int mf = 0; mf < 4; mf++)
#pragma unroll
        for (int nf = 0; nf < 8; nf++) acc[mf][nf] = (f32x4){0.f, 0.f, 0.f, 0.f};

    cp16(aB0, &Als[t * 8]);
    cp16(aB1, &Als[2048 + t * 8]);
    cp16(bB, &Bls[t * 8]);
    cp16(bB + 64 * 256, &Bls[2048 + t * 8]);
    cp16(bB + 128 * 256, &Bls[4096 + t * 8]);
    cp16(bB + 192 * 256, &Bls[6144 + t * 8]);
    __syncthreads();

    int l = t & 63, wid = t >> 6, wm = wid >> 1, wn = wid & 1;
    int arow = wm * 64 + (l & 15);
    int brow = wn * 128 + (l & 15);
    int pslot = ((l >> 4) ^ ((l >> 1) & 3)) * 8;

    for (int s = 0; s < 8; s++) {
        int cur = s & 1;
        if (s < 7) {
            int off = (s + 1) * 32;
            int nb = cur ^ 1;
            cp16(aB0 + off, &Als[nb * 4096 + t * 8]);
            cp16(aB1 + off, &Als[nb * 4096 + 2048 + t * 8]);
            cp16(bB + off, &Bls[nb * 8192 + t * 8]);
            cp16(bB + 64 * 256 + off, &Bls[nb * 8192 + 2048 + t * 8]);
            cp16(bB + 128 * 256 + off, &Bls[nb * 8192 + 4096 + t * 8]);
            cp16(bB + 192 * 256 + off, &Bls[nb * 8192 + 6144 + t * 8]);
        }
        short8 af[4], bf[8];
#pragma unroll
        for (int mf = 0; mf < 4; mf++)
            af[mf] = *(const short8*)&Als[cur * 4096 + (arow + mf * 16) * 32 + pslot];
#pragma unroll
        for (int nf = 0; nf < 8; nf++)
            bf[nf] = *(const short8*)&Bls[cur * 8192 + (brow + nf * 16) * 32 + pslot];
#pragma unroll
        for (int mf = 0; mf < 4; mf++)
#pragma unroll
            for (int nf = 0; nf < 8; nf++)
                acc[mf][nf] = __builtin_amdgcn_mfma_f32_16x16x32_bf16(
                    af[mf], bf[nf], acc[mf][nf], 0, 0, 0);
        __syncthreads();
    }

    // ---- write conv result (+bias) to LDS tile T[128][256] bf16 ----
#pragma unroll
    for (int nf = 0; nf < 8; nf++) {
        int o = wn * 128 + nf * 16 + (l & 15);
        float bias = frb[o];
#pragma unroll
        for (int mf = 0; mf < 4; mf++) {
            int rbase = wm * 64 + mf * 16 + ((l >> 4) << 2);
            f32x4 a = acc[mf][nf];
#pragma unroll
            for (int jj = 0; jj < 4; jj++)
                sh[(rbase + jj) * 256 + o] = f2bf(a[jj] + bias);
        }
    }
    __syncthreads();

    // ---- pool (vectorized): thread = (w2, 8-o group); b128 row reads ----
    {
        int h2 = mt & 31;
        size_t rowb = (size_t)(b << 10) + h2 * 32;
        int o0 = (t & 31) * 8;
#pragma unroll
        for (int pp = 0; pp < 4; pp++) {
            int w2 = pp * 8 + (t >> 5);
            u16x8 r0 = *(const u16x8*)&sh[(2 * w2) * 256 + o0];
            u16x8 r1 = *(const u16x8*)&sh[(2 * w2 + 1) * 256 + o0];
            u16x8 r2 = *(const u16x8*)&sh[(64 + 2 * w2) * 256 + o0];
            u16x8 r3 = *(const u16x8*)&sh[(64 + 2 * w2 + 1) * 256 + o0];
            u16x8 pv;
            unsigned amlo = 0, amhi = 0;
#pragma unroll
            for (int e = 0; e < 8; e++) {
                float v0 = bf2f(r0[e]), v1 = bf2f(r1[e]);
                float v2 = bf2f(r2[e]), v3 = bf2f(r3[e]);
                float m = v0;
                ushort_t raw = r0[e];
                unsigned am = 0;
                if (v1 > m) { m = v1; raw = r1[e]; am = 1; }
                if (v2 > m) { m = v2; raw = r2[e]; am = 2; }
                if (v3 > m) { m = v3; raw = r3[e]; am = 3; }
                pv[e] = raw;
                if (e < 4) amlo |= am << (8 * e);
                else       amhi |= am << (8 * (e - 4));
            }
            size_t po = (rowb + w2) * 256 + o0;
            *(u16x8*)(Pbf + po) = pv;
            *(uint2*)(idx + po) = make_uint2(amlo, amhi);
        }
    }
}

// ---------- K2a: QKV MFMA GEMM. q prescaled by RSCALE; v stored transposed ----------
__global__ __launch_bounds__(256) void k_qkv_mfma(
    const ushort_t* __restrict__ A, const ushort_t* __restrict__ Bw,
    ushort_t* __restrict__ qb, ushort_t* __restrict__ kb,
    ushort_t* __restrict__ vtb) {
    __shared__ __align__(16) ushort_t Als[2][4096];
    __shared__ __align__(16) ushort_t Bls[2][4096];
    int t = threadIdx.x;
    int wg = blockIdx.x;
    int linear = (wg & 7) * 96 + (wg >> 3);  // 768 wgs; nt inner for A reuse
    int mt = linear / 6, nt = linear % 6;

    int r = t >> 2, p = t & 3;
    int kswz = (p ^ ((r >> 1) & 3)) * 8;
    const ushort_t* aB0 = A + ((size_t)(mt * 128 + r)) * 256 + kswz;
    const ushort_t* aB1 = aB0 + (size_t)64 * 256;
    const ushort_t* bB0 = Bw + ((size_t)(nt * 128 + r)) * 256 + kswz;
    const ushort_t* bB1 = bB0 + (size_t)64 * 256;

    f32x4 acc[4][4];
#pragma unroll
    for (int mf = 0; mf < 4; mf++)
#pragma unroll
        for (int nf = 0; nf < 4; nf++) acc[mf][nf] = (f32x4){0.f, 0.f, 0.f, 0.f};

    cp16(aB0, &Als[0][t * 8]);
    cp16(aB1, &Als[0][2048 + t * 8]);
    cp16(bB0, &Bls[0][t * 8]);
    cp16(bB1, &Bls[0][2048 + t * 8]);
    __syncthreads();

    int l = t & 63, wid = t >> 6, wm = wid >> 1, wn = wid & 1;
    int arow = wm * 64 + (l & 15);
    int brow = wn * 64 + (l & 15);
    int pslot = ((l >> 4) ^ ((l >> 1) & 3)) * 8;

    for (int s = 0; s < 8; s++) {
        int cur = s & 1;
        if (s < 7) {
            int off = (s + 1) * 32;
            int nb = cur ^ 1;
            cp16(aB0 + off, &Als[nb][t * 8]);
            cp16(aB1 + off, &Als[nb][2048 + t * 8]);
            cp16(bB0 + off, &Bls[nb][t * 8]);
            cp16(bB1 + off, &Bls[nb][2048 + t * 8]);
        }
        short8 af[4], bf[4];
#pragma unroll
        for (int mf = 0; mf < 4; mf++)
            af[mf] = *(const short8*)&Als[cur][(arow + mf * 16) * 32 + pslot];
#pragma unroll
        for (int nf = 0; nf < 4; nf++)
            bf[nf] = *(const short8*)&Bls[cur][(brow + nf * 16) * 32 + pslot];
#pragma unroll
        for (int mf = 0; mf < 4; mf++)
#pragma unroll
            for (int nf = 0; nf < 4; nf++)
                acc[mf][nf] = __builtin_amdgcn_mfma_f32_16x16x32_bf16(
                    af[mf], bf[nf], acc[mf][nf], 0, 0, 0);
        __syncthreads();
    }

    if (nt < 4) {
        // q (scaled) / k: [m][256] bf16 scatter
        ushort_t* dst = (nt < 2) ? qb : kb;
        float sc = (nt < 2) ? RSCALE : 1.0f;
        int ccb = (nt & 1) * 128 + wn * 64;
#pragma unroll
        for (int nf = 0; nf < 4; nf++) {
            int cc = ccb + nf * 16 + (l & 15);
#pragma unroll
            for (int mf = 0; mf < 4; mf++) {
                int m = mt * 128 + wm * 64 + mf * 16 + ((l >> 4) << 2);
                f32x4 a = acc[mf][nf];
#pragma unroll
                for (int jj = 0; jj < 4; jj++)
                    dst[(size_t)(m + jj) * 256 + cc] = f2bf(a[jj] * sc);
            }
        }
    } else {
        // v transposed: vtb[(b*256 + cc)][n], 4 consecutive n per lane -> uint2
#pragma unroll
        for (int nf = 0; nf < 4; nf++) {
            int cc = (nt & 1) * 128 + wn * 64 + nf * 16 + (l & 15);
#pragma unroll
            for (int mf = 0; mf < 4; mf++) {
                int m = mt * 128 + wm * 64 + mf * 16 + ((l >> 4) << 2);
                int b = m >> 10, n0 = m & 1023;
                f32x4 a = acc[mf][nf];
                unsigned u0 = ((unsigned)f2bf(a[1]) << 16) | f2bf(a[0]);
                unsigned u1 = ((unsigned)f2bf(a[3]) << 16) | f2bf(a[2]);
                *(uint2*)&vtb[((size_t)(b * 256 + cc)) * 1024 + n0] =
                    make_uint2(u0, u1);
            }
        }
    }
}

// ---------- K2b: MFMA flash attention (swapped QK^T, wave-private P_lds) ----------
__global__ __launch_bounds__(256) void k_attn_mfma(
    const ushort_t* __restrict__ qb, const ushort_t* __restrict__ kb,
    const ushort_t* __restrict__ vtb, ushort_t* __restrict__ aoT) {
    __shared__ __align__(16) ushort_t Klds[2][2048];   // [64 k][32 d] swizzled
    __shared__ __align__(16) ushort_t Vlds[2][2048];   // [32 d][64 n] swizzled
    __shared__ __align__(16) ushort_t Plds[4][2304];   // per-wave [32 q][72]
    __shared__ float rs_lds[128];

    int t = threadIdx.x;
    int bid = blockIdx.x;
    int swz = (bid & 7) * 128 + (bid >> 3);
    int bh = swz >> 3, qt = swz & 7;
    int b = bh >> 3, h = bh & 7;
    int w = t >> 6, l = t & 63, g = l >> 4, li = l & 15;

    // Q B-frags
    size_t qrow = (size_t)(b * 1024 + qt * 128 + w * 32 + li);
    short8 qv0 = *(const short8*)(qb + qrow * 256 + h * 32 + g * 8);
    short8 qv1 = *(const short8*)(qb + (qrow + 16) * 256 + h * 32 + g * 8);

    // staging addresses (XOR-preswizzled global source, linear LDS dest)
    int sr = t >> 2, sp = t & 3;
    const ushort_t* kg =
        kb + ((size_t)(b * 1024 + sr)) * 256 + h * 32 + ((sp ^ ((sr >> 1) & 3)) * 8);
    int vd = t >> 3, vs = t & 7;
    const ushort_t* vg =
        vtb + ((size_t)(b * 256 + h * 32 + vd)) * 1024 + ((vs ^ (vd & 7)) * 8);

    f32x4 oacc[2][2];
    f32x4 rsv[2];
#pragma unroll
    for (int qf = 0; qf < 2; qf++) {
        rsv[qf] = (f32x4){0.f, 0.f, 0.f, 0.f};
#pragma unroll
        for (int df = 0; df < 2; df++) oacc[qf][df] = (f32x4){0.f, 0.f, 0.f, 0.f};
    }

    cp16(kg, &Klds[0][t * 8]);
    cp16(vg, &Vlds[0][t * 8]);
    __syncthreads();

    ushort_t* Pw = &Plds[w][0];

    for (int c = 0; c < 16; c++) {
        int cur = c & 1;
        if (c < 15) {  // async prefetch next chunk; drains at this step's barrier
            cp16(kg + (size_t)(c + 1) * 64 * 256, &Klds[cur ^ 1][t * 8]);
            cp16(vg + (c + 1) * 64, &Vlds[cur ^ 1][t * 8]);
        }
        // S^T frags: A = K rows, B = Q rows. D: col=q(li), row=k(4g+reg)
        short8 ak[4];
#pragma unroll
        for (int kf = 0; kf < 4; kf++)
            ak[kf] = *(const short8*)&Klds[cur][(16 * kf + li) * 32 +
                                               ((g ^ ((l >> 1) & 3)) * 8)];
#pragma unroll
        for (int qf = 0; qf < 2; qf++) {
            short8 qv = qf ? qv1 : qv0;
#pragma unroll
            for (int kf = 0; kf < 4; kf++) {
                f32x4 st = __builtin_amdgcn_mfma_f32_16x16x32_bf16(
                    ak[kf], qv, (f32x4){0.f, 0.f, 0.f, 0.f}, 0, 0, 0);
                float p0 = __expf(st[0]), p1 = __expf(st[1]);
                float p2 = __expf(st[2]), p3 = __expf(st[3]);
                rsv[qf][0] += p0; rsv[qf][1] += p1;
                rsv[qf][2] += p2; rsv[qf][3] += p3;
                unsigned u0, u1;
                asm("v_cvt_pk_bf16_f32 %0, %1, %2" : "=v"(u0) : "v"(p0), "v"(p1));
                asm("v_cvt_pk_bf16_f32 %0, %1, %2" : "=v"(u1) : "v"(p2), "v"(p3));
                *(uint2*)&Pw[(16 * qf + li) * 72 + 16 * kf + 4 * g] =
                    make_uint2(u0, u1);
            }
        }
        // PV: A = P rows (q), B = vT rows (d). D: col=d(li), row=q(4g+reg)
#pragma unroll
        for (int win = 0; win < 2; win++) {
            short8 pa[2], bv[2];
#pragma unroll
            for (int qf = 0; qf < 2; qf++)
                pa[qf] = *(const short8*)&Pw[(16 * qf + li) * 72 + win * 32 + 8 * g];
#pragma unroll
            for (int df = 0; df < 2; df++)
                bv[df] = *(const short8*)&Vlds[cur][(16 * df + li) * 64 +
                                                    (((win * 4 + g) ^ (l & 7)) * 8)];
#pragma unroll
            for (int qf = 0; qf < 2; qf++)
#pragma unroll
                for (int df = 0; df < 2; df++)
                    oacc[qf][df] = __builtin_amdgcn_mfma_f32_16x16x32_bf16(
                        pa[qf], bv[df], oacc[qf][df], 0, 0, 0);
        }
        __syncthreads();
    }

    // row-sum: reduce partials over the 4 g-groups
#pragma unroll
    for (int qf = 0; qf < 2; qf++) {
        float rs = (rsv[qf][0] + rsv[qf][1]) + (rsv[qf][2] + rsv[qf][3]);
        rs += __shfl_xor(rs, 16);
        rs += __shfl_xor(rs, 32);
        if (l < 16) rs_lds[w * 32 + 16 * qf + li] = rs;
    }
    __syncthreads();

    // epilogue: O lane holds q = 16qf + 4g + reg, d = 16df + li
#pragma unroll
    for (int qf = 0; qf < 2; qf++) {
        float4 rs4 = *(const float4*)&rs_lds[w * 32 + 16 * qf + 4 * g];
        float inv[4] = {1.f / rs4.x, 1.f / rs4.y, 1.f / rs4.z, 1.f / rs4.w};
#pragma unroll
        for (int df = 0; df < 2; df++) {
            f32x4 a = oacc[qf][df];
#pragma unroll
            for (int r2 = 0; r2 < 4; r2++) {
                size_t row = (size_t)(b * 1024 + qt * 128 + w * 32 + 16 * qf +
                                      4 * g + r2);
                aoT[row * 256 + h * 32 + 16 * df + li] = f2bf(a[r2] * inv[r2]);
            }
        }
    }
}

// ---------- K2c: output projection MFMA -> y2 [b][n][o] fp32 ----------
__global__ __launch_bounds__(256) void k_oproj_mfma(
    const ushort_t* __restrict__ A, const ushort_t* __restrict__ Bw,
    float* __restrict__ y2) {
    __shared__ __align__(16) ushort_t Als[2][4096];
    __shared__ __align__(16) ushort_t Bls[2][4096];
    int t = threadIdx.x;
    int wg = blockIdx.x;
    int linear = (wg & 7) * 32 + (wg >> 3);  // 256 wgs; nt inner
    int nt = linear & 1, mt = linear >> 1;

    int r = t >> 2, p = t & 3;
    int kswz = (p ^ ((r >> 1) & 3)) * 8;
    const ushort_t* aB0 = A + ((size_t)(mt * 128 + r)) * 256 + kswz;
    const ushort_t* aB1 = aB0 + (size_t)64 * 256;
    const ushort_t* bB0 = Bw + ((size_t)(nt * 128 + r)) * 256 + kswz;
    const ushort_t* bB1 = bB0 + (size_t)64 * 256;

    f32x4 acc[4][4];
#pragma unroll
    for (int mf = 0; mf < 4; mf++)
#pragma unroll
        for (int nf = 0; nf < 4; nf++) acc[mf][nf] = (f32x4){0.f, 0.f, 0.f, 0.f};

    cp16(aB0, &Als[0][t * 8]);
    cp16(aB1, &Als[0][2048 + t * 8]);
    cp16(bB0, &Bls[0][t * 8]);
    cp16(bB1, &Bls[0][2048 + t * 8]);
    __syncthreads();

    int l = t & 63, wid = t >> 6, wm = wid >> 1, wn = wid & 1;
    int arow = wm * 64 + (l & 15);
    int brow = wn * 64 + (l & 15);
    int pslot = ((l >> 4) ^ ((l >> 1) & 3)) * 8;

    for (int s = 0; s < 8; s++) {
        int cur = s & 1;
        if (s < 7) {
            int off = (s + 1) * 32;
            int nb = cur ^ 1;
            cp16(aB0 + off, &Als[nb][t * 8]);
            cp16(aB1 + off, &Als[nb][2048 + t * 8]);
            cp16(bB0 + off, &Bls[nb][t * 8]);
            cp16(bB1 + off, &Bls[nb][2048 + t * 8]);
        }
        short8 af[4], bf[4];
#pragma unroll
        for (int mf = 0; mf < 4; mf++)
            af[mf] = *(const short8*)&Als[cur][(arow + mf * 16) * 32 + pslot];
#pragma unroll
        for (int nf = 0; nf < 4; nf++)
            bf[nf] = *(const short8*)&Bls[cur][(brow + nf * 16) * 32 + pslot];
#pragma unroll
        for (int mf = 0; mf < 4; mf++)
#pragma unroll
            for (int nf = 0; nf < 4; nf++)
                acc[mf][nf] = __builtin_amdgcn_mfma_f32_16x16x32_bf16(
                    af[mf], bf[nf], acc[mf][nf], 0, 0, 0);
        __syncthreads();
    }

#pragma unroll
    for (int nf = 0; nf < 4; nf++) {
        int cc = nt * 128 + wn * 64 + nf * 16 + (l & 15);
#pragma unroll
        for (int mf = 0; mf < 4; mf++) {
            int m = mt * 128 + wm * 64 + mf * 16 + ((l >> 4) << 2);
            f32x4 a = acc[mf][nf];
#pragma unroll
            for (int jj = 0; jj < 4; jj++)
                y2[(size_t)(m + jj) * 256 + cc] = a[jj];
        }
    }
}

// ---------- K3: implicit-GEMM bf16 MFMA 3x3 conv ----------
// Session-best config (round 9, 100.0-100.7 us verified 3x): BM=128 BN=256
// BK=32, 8 waves, B in LDS, 2 blocks/CU, 3 LDS buffers (72 KB dynamic),
// counted vmcnt(3) + raw s_barrier, 16x16x32 MFMA. Plateau is structural:
// the two resident 8-wave blocks phase-align; per-CU window = MFMA 37% +
// LDS reads 46% + barriers, summing. 8 structural variants (barrier count,
// phase order, reg pipelining, A-window, B-direct, 2-deep staging,
// residency, 32x32 MFMA [9.4M bank conflicts]) bracketed this optimum.
__global__ __launch_bounds__(512, 4) void k_conv3_mfma(
    const ushort_t* __restrict__ xn, const ushort_t* __restrict__ wbfT,
    const float* __restrict__ cb, const float* __restrict__ y2,
    const unsigned char* __restrict__ idx, const float* __restrict__ gamma,
    float* __restrict__ out) {
    extern __shared__ __align__(16) ushort_t lds[];  // 3 bufs x 12288 ushorts
    int t = threadIdx.x;
    int wg = blockIdx.x;
    int mt = (wg & 7) * 64 + (wg >> 3);  // 512 wgs; XCD swizzle

    // staging: thread t covers (row t>>2, 16B slot t&3); swz f(row)=(row>>1)&3
    int srow = t >> 2, sslot = t & 3;
    int kel = (sslot ^ ((srow >> 1) & 3)) * 8;  // elements
    int m0 = mt * 128 + srow;
    int ab0 = m0 >> 12, ah0 = (m0 >> 6) & 63, aw0 = m0 & 63;
    const ushort_t* aP = xn + ((size_t)((ab0 * 66 + ah0) * 66 + aw0)) * 256 + kel;
    const ushort_t* bP0 = wbfT + (size_t)srow * 256 + kel;          // rows 0..127
    const ushort_t* bP1 = wbfT + (size_t)(srow + 128) * 256 + kel;  // rows 128..255

    // kt = it*9 + khkw; it in 0..7 (32-ch slice), khkw in 0..8 (spatial tap)
    auto offA = [](int kt) -> int {
        int it = kt / 9, khkw = kt - it * 9;
        int kh = khkw / 3, kw = khkw - kh * 3;
        return (kh * 66 + kw) * 256 + it * 32;
    };
    auto offB = [](int kt) -> int {
        int it = kt / 9, khkw = kt - it * 9;
        return khkw * 65536 + it * 32;
    };
    auto STAGE = [&](int bufi, int kt) {  // 3 cp16/thread: A 8KB + B 16KB
        ushort_t* base = lds + bufi * 12288;
        cp16(aP + offA(kt), base + t * 8);
        int ob = offB(kt);
        cp16(bP0 + ob, base + 4096 + t * 8);
        cp16(bP1 + ob, base + 8192 + t * 8);
    };

    f32x4 acc[4][4];
#pragma unroll
    for (int mf = 0; mf < 4; mf++)
#pragma unroll
        for (int nf = 0; nf < 4; nf++) acc[mf][nf] = (f32x4){0.f, 0.f, 0.f, 0.f};

    int l = t & 63, wid = t >> 6, wm = wid >> 2, wn = wid & 3;
    int lr = l & 15, g = l >> 4;
    int fslot = (g ^ ((lr >> 1) & 3)) * 8;  // cancels staging swizzle

    // prologue: tiles 0,1 in flight; drain tile 0; barrier
    STAGE(0, 0);
    STAGE(1, 1);
    __builtin_amdgcn_sched_barrier(0);
    asm volatile("s_waitcnt vmcnt(3)" ::: "memory");
    __builtin_amdgcn_sched_barrier(0);
    __builtin_amdgcn_s_barrier();
    __builtin_amdgcn_sched_barrier(0);

    for (int kt = 0; kt < 72; kt++) {
        int cur = kt % 3;
        const ushort_t* base = lds + cur * 12288;
        if (kt < 70) STAGE((kt + 2) % 3, kt + 2);
        short8 af[4], bf[4];
#pragma unroll
        for (int mf = 0; mf < 4; mf++)
            af[mf] = *(const short8*)&base[(wm * 64 + mf * 16 + lr) * 32 + fslot];
#pragma unroll
        for (int nf = 0; nf < 4; nf++)
            bf[nf] = *(const short8*)&base[4096 + (wn * 64 + nf * 16 + lr) * 32 +
                                           fslot];
        __builtin_amdgcn_s_setprio(1);
#pragma unroll
        for (int mf = 0; mf < 4; mf++)
#pragma unroll
            for (int nf = 0; nf < 4; nf++)
                acc[mf][nf] = __builtin_amdgcn_mfma_f32_16x16x32_bf16(
                    af[mf], bf[nf], acc[mf][nf], 0, 0, 0);
        __builtin_amdgcn_s_setprio(0);
        __builtin_amdgcn_sched_barrier(0);
        if (kt < 70) {
            asm volatile("s_waitcnt vmcnt(3)" ::: "memory");  // drains kt+1's 3
        } else {
            asm volatile("s_waitcnt vmcnt(0)" ::: "memory");
        }
        __builtin_amdgcn_sched_barrier(0);
        __builtin_amdgcn_s_barrier();
        __builtin_amdgcn_sched_barrier(0);
    }

    float tg = tanhf(gamma[0]);
    int mbase = mt * 128 + wm * 64 + (g << 2);
    int obase = wn * 64 + lr;
#pragma unroll
    for (int nf = 0; nf < 4; nf++) {
        int o = obase + nf * 16;
        float bias = cb[o];
#pragma unroll
        for (int mf = 0; mf < 4; mf++) {
            int m = mbase + mf * 16;
            int b = m >> 12, h = (m >> 6) & 63, w0 = m & 63;
            const unsigned char* idr = idx + ((size_t)(b << 10)) * 256;
            const float* y2r = y2 + ((size_t)(b << 10)) * 256;
            f32x4 a = acc[mf][nf];
            float v4[4];
#pragma unroll
            for (int jj = 0; jj < 4; jj++) {
                int wj = w0 + jj;
                int n2 = ((h >> 1) << 5) + (wj >> 1);
                int j2 = ((h & 1) << 1) + (wj & 1);
                float val = a[jj] + bias;
                if (idr[(size_t)n2 * 256 + o] == (unsigned char)j2)
                    val += tg * y2r[(size_t)n2 * 256 + o];
                v4[jj] = val;
            }
            *(float4*)(out + (((size_t)(b * C + o) * H + h) << 6) + w0) =
                make_float4(v4[0], v4[1], v4[2], v4[3]);
        }
    }
}

extern "C" void kernel_launch(void* const* d_in, const int* in_sizes, int n_in,
                              void* d_out, int out_size, void* d_ws, size_t ws_size,
                              hipStream_t stream) {
    const float* x      = (const float*)d_in[0];
    const float* conv_w = (const float*)d_in[1];
    const float* conv_b = (const float*)d_in[2];
    const float* fr_w   = (const float*)d_in[3];
    const float* fr_b   = (const float*)d_in[4];
    const float* wq     = (const float*)d_in[5];
    const float* wk     = (const float*)d_in[6];
    const float* wv     = (const float*)d_in[7];
    const float* wo     = (const float*)d_in[8];
    const float* gamma  = (const float*)d_in[9];
    float* out = (float*)d_out;
    char* ws = (char*)d_ws;

    // ws layout (bytes), total 83.9 MB
    ushort_t* wbfT  = (ushort_t*)(ws + 0);           // 1,179,648
    ushort_t* wfrbf = (ushort_t*)(ws + 1179648);     // 131,072
    ushort_t* wqkvT = (ushort_t*)(ws + 1310720);     // 393,216
    ushort_t* woT   = (ushort_t*)(ws + 1703936);     // 131,072
    ushort_t* xn    = (ushort_t*)(ws + 2097152);     // 35,684,352
    ushort_t* Pbf   = (ushort_t*)(ws + 37781504);    // 8,388,608
    unsigned char* idx = (unsigned char*)(ws + 46170112);  // 4,194,304
    ushort_t* qb    = (ushort_t*)(ws + 50364416);    // 8,388,608
    ushort_t* kb    = (ushort_t*)(ws + 58753024);    // 8,388,608
    ushort_t* vtb   = (ushort_t*)(ws + 67141632);    // 8,388,608 (transposed V)
    ushort_t* aoT   = (ushort_t*)(ws + 75530240);    // 8,388,608 -> end 83,918,848
    float* y2       = (float*)(ws + 50364416);       // aliases qb+kb (dead after attn)

    k_prep_wx<<<dim3(256, 6), dim3(256), 0, stream>>>(wq, wk, wv, wo, fr_w, conv_w,
                                                      wqkvT, woT, wfrbf, wbfT);
    k_prep_xn<<<dim3(66, B), dim3(256), 0, stream>>>(x, xn);
    k_conv1pool_mfma<<<dim3(512), dim3(256), 0, stream>>>(xn, wfrbf, fr_b, Pbf, idx);
    k_qkv_mfma<<<dim3(768), dim3(256), 0, stream>>>(Pbf, wqkvT, qb, kb, vtb);
    k_attn_mfma<<<dim3(1024), dim3(256), 0, stream>>>(qb, kb, vtb, aoT);
    k_oproj_mfma<<<dim3(256), dim3(256), 0, stream>>>(aoT, woT, y2);
    (void)hipFuncSetAttribute(reinterpret_cast<const void*>(k_conv3_mfma),
                              hipFuncAttributeMaxDynamicSharedMemorySize, 73728);
    k_conv3_mfma<<<dim3(512), dim3(512), 73728, stream>>>(xn, wbfT, conv_b, y2, idx,
                                                          gamma, out);
    (void)in_sizes; (void)n_in; (void)out_size; (void)ws_size;
}